// Round 11
// baseline (2392.082 us; speedup 1.0000x reference)
//
#include <hip/hip_runtime.h>

#define B_    64
#define L1C   4093
#define L2C   4086
#define L3C   4071
#define TDEC  60

static __device__ __forceinline__ float sigf(float x){ return 1.f/(1.f + __expf(-x)); }

// ---------------- f16 pack / dot helpers ----------------
typedef _Float16 h2_t __attribute__((ext_vector_type(2)));
union U2H { unsigned u; h2_t h; };

static __device__ __forceinline__ unsigned pkh2(float a, float b){
  U2H r; r.h[0] = (_Float16)a; r.h[1] = (_Float16)b; return r.u;
}
// acc += dot(w_half2, h_half2) in fp32 — v_dot2_f32_f16 (full-rate VOP3P)
static __device__ __forceinline__ float dot2f(unsigned w, unsigned h, float acc){
  U2H a; a.u = w; U2H b; b.u = h;
#if __has_builtin(__builtin_amdgcn_fdot2)
  return __builtin_amdgcn_fdot2(a.h, b.h, acc, false);
#else
  acc = fmaf((float)a.h[0], (float)b.h[0], acc);
  acc = fmaf((float)a.h[1], (float)b.h[1], acc);
  return acc;
#endif
}

// 8 MACs from one uint4 of packed f16 weights x one uint4 of packed f16 h
#define DOT8(g, wv, hv) \
  g = dot2f(wv.x, hv.x, g); g = dot2f(wv.y, hv.y, g); \
  g = dot2f(wv.z, hv.z, g); g = dot2f(wv.w, hv.w, g);

// DPP-fused add: x + dpp_perm(x). VALU-pipe, replaces ds_swizzle shuffles.
// 0xB1 = quad_perm xor1, 0x4E = quad_perm xor2, 0x124/0x128 = row_ror:4/8.
template<int CTRL>
static __device__ __forceinline__ float dppadd(float x){
  int y = __builtin_amdgcn_update_dpp(0, __float_as_int(x), CTRL, 0xf, 0xf, true);
  return x + __int_as_float(y);
}

// ---------------- convs: LDS-staged input (coalesced), scalar fmaf ----------------
template<int CIN,int COUT,int KW,int CINP>
__global__ __launch_bounds__(256) void k_convL(
    const float* __restrict__ in, const float* __restrict__ w,
    const float* __restrict__ bias, float* __restrict__ outp,
    int Lin_, int Lout_)
{
  __shared__ float xs[(256+KW-1)*CINP];
  int bi = blockIdx.y, l0 = blockIdx.x*256, tid = threadIdx.x;
  int nrow = min(256+KW-1, Lin_-l0);
  const float* ip = in + ((size_t)bi*Lin_ + l0)*CIN;
  for (int i = tid; i < nrow*(CIN/4); i += 256){
    int rr = i/(CIN/4), cc = i - rr*(CIN/4);
    float4 v = *(const float4*)(ip + rr*CIN + cc*4);
    float* dst = &xs[rr*CINP + cc*4];
    dst[0]=v.x; dst[1]=v.y; dst[2]=v.z; dst[3]=v.w;
  }
  __syncthreads();
  int l = l0 + tid;
  if (l >= Lout_) return;
  float acc[COUT];
#pragma unroll
  for (int o=0;o<COUT;o++) acc[o] = bias[o];
  for (int k=0;k<KW;k++){
    const float* xr = &xs[(tid+k)*CINP];
#pragma unroll
    for (int i=0;i<CIN;i++){
      float xv = xr[i];
#pragma unroll
      for (int o=0;o<COUT;o++)
        acc[o] = fmaf(xv, w[(o*CIN + i)*KW + k], acc[o]);
    }
  }
  float* op = outp + ((size_t)bi*Lout_ + l)*COUT;
#pragma unroll
  for (int o=0;o<COUT;o++) op[o] = fmaxf(acc[o], 0.f);
}

// conv3: LDS-staged + scalar fmaf + relu + row-quantize to u8 (scale = rowmax/255)
__global__ __launch_bounds__(256) void k_conv3qL(
    const float* __restrict__ in, const float* __restrict__ w,
    const float* __restrict__ bias, uint4* __restrict__ encq,
    float* __restrict__ encs, int Lin_, int Lout_)
{
  __shared__ float xs[(256+15)*17];
  int bi = blockIdx.y, l0 = blockIdx.x*256, tid = threadIdx.x;
  int nrow = min(256+15, Lin_-l0);
  const float* ip = in + ((size_t)bi*Lin_ + l0)*16;
  for (int i = tid; i < nrow*4; i += 256){
    int rr = i>>2, cc = i&3;
    float4 v = *(const float4*)(ip + rr*16 + cc*4);
    float* dst = &xs[rr*17 + cc*4];
    dst[0]=v.x; dst[1]=v.y; dst[2]=v.z; dst[3]=v.w;
  }
  __syncthreads();
  int l = l0 + tid;
  if (l >= Lout_) return;
  float acc[32];
#pragma unroll
  for (int o=0;o<32;o++) acc[o] = bias[o];
  for (int k=0;k<16;k++){
    const float* xr = &xs[(tid+k)*17];
#pragma unroll
    for (int i=0;i<16;i++){
      float xv = xr[i];
#pragma unroll
      for (int o=0;o<32;o++)
        acc[o] = fmaf(xv, w[(o*16 + i)*16 + k], acc[o]);
    }
  }
  float mx = 0.f;
#pragma unroll
  for (int o=0;o<32;o++){ acc[o] = fmaxf(acc[o],0.f); mx = fmaxf(mx, acc[o]); }
  float scale = mx * (1.f/255.f);
  float inv = (mx > 0.f) ? (255.f/mx) : 0.f;
  unsigned qs[8];
#pragma unroll
  for (int q8=0;q8<8;q8++){
    unsigned q0 = (unsigned)(acc[q8*4+0]*inv + 0.5f);
    unsigned q1 = (unsigned)(acc[q8*4+1]*inv + 0.5f);
    unsigned q2 = (unsigned)(acc[q8*4+2]*inv + 0.5f);
    unsigned q3 = (unsigned)(acc[q8*4+3]*inv + 0.5f);
    qs[q8] = q0 | (q1<<8) | (q2<<16) | (q3<<24);
  }
  uint4* op = encq + ((size_t)bi*Lout_ + l)*2;
  op[0] = make_uint4(qs[0],qs[1],qs[2],qs[3]);
  op[1] = make_uint4(qs[4],qs[5],qs[6],qs[7]);
  encs[(size_t)bi*Lout_ + l] = scale;
}

// ---------------- pack weights: [2][1024][K] fp32 -> [2][K/8][1024] f16x8 ----------------
__global__ __launch_bounds__(256) void k_packwh(
    const float* __restrict__ w, uint4* __restrict__ wT, int K)
{
  int gid = blockIdx.x*256 + threadIdx.x;
  int per = (K/8)*1024;
  int d = gid / per, rem = gid - d*per;
  int j8 = rem >> 10, row = rem & 1023;
  const float* src = w + ((size_t)d*1024 + row)*K + j8*8;
  float4 a = *(const float4*)src;
  float4 b = *(const float4*)(src+4);
  uint4 o;
  o.x = pkh2(a.x, a.y);
  o.y = pkh2(a.z, a.w);
  o.z = pkh2(b.x, b.y);
  o.w = pkh2(b.z, b.w);
  wT[gid] = o;
}

#define CVT8(r, qv) \
  r[0]=(float)( qv.x      & 255u); r[1]=(float)((qv.x>>8 ) & 255u); \
  r[2]=(float)((qv.x>>16) & 255u); r[3]=(float)((qv.x>>24)       ); \
  r[4]=(float)( qv.y      & 255u); r[5]=(float)((qv.y>>8 ) & 255u); \
  r[6]=(float)((qv.y>>16) & 255u); r[7]=(float)((qv.y>>24)       );

// ---------------- dec1: block=(b,d); enc u8 in LDS; quad split (8ch/thread) ----------------
// SINGLE-VARIABLE PROBE: amdgpu_waves_per_eu(4,4) — max-occupancy declaration
// frees the allocator to use up to 512/4=128 VGPRs (LDS=156KB already caps at
// 1 WG/CU = 4 waves/EU, so this costs nothing). wpre[12] preload (48 VGPR) cuts
// the per-step whh L2 stream 37.5%. R7/R8 proved launch_bounds(,4) is inert
// (min-waves semantics); R8->R9 rec2 delta suggests THIS attribute works.
// Readout: VGPR_Count ~108 + FETCH ~9.4e3 = works; VGPR 64 + FETCH 3e6 = spill.
__global__ __launch_bounds__(1024) __attribute__((amdgpu_waves_per_eu(4,4)))
void k_dec1g(
    const uint4* __restrict__ encq,        // [B][L3C][2] uint4 (32 x u8)
    const float* __restrict__ encs,        // [B][L3C] rowscale
    const float* __restrict__ attn_w,      // [256][32]
    const uint4* __restrict__ wihT,        // [2][4][1024] f16x8 (K=32)
    const uint4* __restrict__ whhT,        // [2][32][1024] f16x8 (K=256)
    const float* __restrict__ bih, const float* __restrict__ bhh,
    float* __restrict__ d2in)              // [B][60][512]
{
  int b = blockIdx.x, d = blockIdx.y, tid = threadIdx.x;
  int c = tid & 3, rb = tid >> 2;          // quad covers rows rb+256k, k=0..15; lane owns ch c*8..c*8+7

  __shared__ __align__(16) uint2 encQ2[16384];  // 128 KB: row l = 4 uint2 (32 x u8)
  __shared__ float sls[4096];                   // 16 KB rowscales
  __shared__ __align__(16) float hls[256];      // fp32 h (attention matvec input)
  __shared__ __align__(16) unsigned h2pk[128];  // h packed f16x2 (gate dot input)
  __shared__ __align__(16) unsigned ctxh[16];   // ctx packed f16x2
  __shared__ float vl[32];
  __shared__ float maxenc[32];
  __shared__ float Msh;
  __shared__ float red[1024];
  __shared__ float scr[512];                    // [16 waves][32 ch]
  __shared__ float gls[1024];

  { // stage enc slice once (uint4-coalesced)
    const uint4* src = encq + (size_t)b*L3C*2;
    uint4* dst = (uint4*)encQ2;
    for (int i = tid; i < 8192; i += 1024)
      dst[i] = (i < L3C*2) ? src[i] : make_uint4(0,0,0,0);
    const float* ss = encs + (size_t)b*L3C;
    for (int i = tid; i < 4096; i += 1024)
      sls[i] = (i < L3C) ? ss[i] : 0.f;
  }
  if (tid < 256) hls[tid] = 0.f;
  if (tid < 128) h2pk[tid] = 0u;
  float creg = 0.f;
  float bsum = bih[(size_t)d*1024 + tid] + bhh[(size_t)d*1024 + tid];
  const uint4* whp = whhT + (size_t)d*32768;
  uint4 wpre[12];                               // rows 0..11 register-resident
#pragma unroll
  for (int j=0;j<12;j++) wpre[j] = whp[j*1024 + tid];
  __syncthreads();

  { // one-time: per-channel max of real enc (>=0) -> maxenc[32]
    float mc[8];
#pragma unroll
    for (int j=0;j<8;j++) mc[j] = 0.f;
#pragma unroll
    for (int k=0;k<16;k++){
      int l = rb + 256*k;
      uint2 qv = encQ2[l*4 + c];
      float sl = sls[l];
      float r[8]; CVT8(r, qv)
#pragma unroll
      for (int j=0;j<8;j++) mc[j] = fmaxf(mc[j], r[j]*sl);
    }
#pragma unroll
    for (int off=4; off<=32; off<<=1){
#pragma unroll
      for (int j=0;j<8;j++) mc[j] = fmaxf(mc[j], __shfl_xor(mc[j], off));
    }
    int wid = tid >> 6;
    if ((tid&63) < 4){
#pragma unroll
      for (int j=0;j<8;j++) scr[wid*32 + c*8 + j] = mc[j];
    }
    __syncthreads();
    if (tid < 32){
      float mm = 0.f;
#pragma unroll
      for (int w=0;w<16;w++) mm = fmaxf(mm, scr[w*32 + tid]);
      maxenc[tid] = mm;
    }
    __syncthreads();
  }

  for (int t=0; t<TDEC; t++){
    // -- phase 1: v[c] = sum_u h[u]*attn_w[u][c]; M = sum_c maxenc[c]*max(v,0) --
    {
      int cc = tid & 31, part = tid >> 5;
      const float* wp = attn_w + (size_t)(part*8)*32 + cc;
      float s = 0.f;
#pragma unroll
      for (int k=0;k<8;k++) s = fmaf(hls[part*8+k], wp[k*32], s);
      red[tid] = s;
    }
    __syncthreads();
    if (tid < 32){
      float v = 0.f;
#pragma unroll
      for (int q=0;q<32;q++) v += red[q*32 + tid];
      vl[tid] = v;
      float mt = maxenc[tid] * fmaxf(v, 0.f);
#pragma unroll
      for (int off=1; off<32; off<<=1) mt += __shfl_xor(mt, off);
      if (tid==0) Msh = mt;
    }
    __syncthreads();

    // -- fused phase 2 (enc scoring, static-bound softmax) + whh·h gate stream --
    float vreg[8];
#pragma unroll
    for (int j=0;j<8;j++) vreg[j] = vl[c*8 + j];
    float M = Msh;
    float ssum = 0.f;
    float acc[8];
#pragma unroll
    for (int j=0;j<8;j++) acc[j] = 0.f;
    float g = bsum;                          // whh dots accumulate here (h stable this step)
#pragma unroll 4
    for (int k=0;k<16;k++){
      uint4 wv0 = (k<6) ? wpre[2*k]   : whp[(2*k  )*1024 + tid];
      uint4 wv1 = (k<6) ? wpre[2*k+1] : whp[(2*k+1)*1024 + tid];
      int l = rb + 256*k;
      uint2 qv = encQ2[l*4 + c];
      float sl = sls[l];
      float r[8]; CVT8(r, qv)
      float s = 0.f;
#pragma unroll
      for (int j=0;j<8;j++) s = fmaf(r[j], vreg[j], s);
      s = dppadd<0xB1>(s);                   // quad xor1 (VALU)
      s = dppadd<0x4E>(s);                   // quad xor2 (VALU)
      s *= sl;
      if (l >= L3C) s = -3.0e38f;            // pad rows (only k=15 can trigger)
      float e = __expf(s - M);
      ssum += e;
      float em = e * sl;
#pragma unroll
      for (int j=0;j<8;j++) acc[j] = fmaf(em, r[j], acc[j]);
      uint4 hv0 = *(const uint4*)&h2pk[(2*k  )*4];
      uint4 hv1 = *(const uint4*)&h2pk[(2*k+1)*4];
      DOT8(g, wv0, hv0)
      DOT8(g, wv1, hv1)
    }
    // reduce across quads: row_ror4+ror8 (VALU) then xor16/xor32 (cross-row)
    ssum = dppadd<0x124>(ssum); ssum = dppadd<0x128>(ssum);
    ssum += __shfl_xor(ssum, 16); ssum += __shfl_xor(ssum, 32);
#pragma unroll
    for (int j=0;j<8;j++){
      acc[j] = dppadd<0x124>(acc[j]); acc[j] = dppadd<0x128>(acc[j]);
      acc[j] += __shfl_xor(acc[j], 16); acc[j] += __shfl_xor(acc[j], 32);
    }
    int wid = tid >> 6;
    if ((tid&63) < 4){
#pragma unroll
      for (int j=0;j<8;j++) scr[wid*32 + c*8 + j] = acc[j];
    }
    if ((tid&63)==0) red[wid] = ssum;
    __syncthreads();
    if (tid < 32){
      float S = 0.f, s2 = 0.f;
#pragma unroll
      for (int w=0;w<16;w++){ S += red[w]; s2 += scr[w*32 + tid]; }
      float cv = s2 / S;
      float co = __shfl_xor(cv, 1);
      if (!(tid&1)) ctxh[tid>>1] = pkh2(cv, co);
    }
    __syncthreads();

    // -- wih·ctx (K=32, streamed — cheap) + nonlinearity --
#pragma unroll
    for (int c8=0;c8<4;c8++){
      uint4 wv = wihT[(size_t)d*4096 + c8*1024 + tid];
      uint4 hv = *(const uint4*)&ctxh[c8*4];
      DOT8(g, wv, hv)
    }
    gls[tid] = g;
    __syncthreads();
    if (tid < 256){
      float ii = sigf(gls[tid]);
      float ff = sigf(gls[256+tid]);
      float gg = tanhf(gls[512+tid]);
      float oo = sigf(gls[768+tid]);
      creg = fmaf(ff, creg, ii*gg);
      float hn = oo * tanhf(creg);
      hls[tid] = hn;
      float ho = __shfl_xor(hn, 1);
      if (!(tid&1)) h2pk[tid>>1] = pkh2(hn, ho);
      int tout = d ? (59 - t) : t;
      d2in[((size_t)b*60 + tout)*512 + d*256 + tid] = hn;
    }
    __syncthreads();
  }
}

// ---------------- fp32 GEMM (out-projection only — keeps final output precision) ----------------
__global__ __launch_bounds__(256) void k_gemm(
    const float* __restrict__ A, const float* __restrict__ W,
    float* __restrict__ C, const float* __restrict__ b1, const float* __restrict__ b2,
    int K, int ldc, size_t sW, size_t sC, int sB)
{
  int m0 = blockIdx.x * 128, n0 = blockIdx.y * 128, z = blockIdx.z;
  const float* Wz = W + (size_t)z*sW;
  float* Cz = C + (size_t)z*sC;
  const float* b1z = b1 + (size_t)z*sB;
  const float* b2z = b2 ? (b2 + (size_t)z*sB) : nullptr;
  __shared__ __align__(16) float As[16][132];
  __shared__ __align__(16) float Bs[16][132];
  int tid = threadIdx.x;
  int tx = tid & 15, ty = tid >> 4;
  int r = tid >> 2, c4 = tid & 3;
  float acc[8][8] = {};
  for (int k0=0; k0<K; k0+=16){
#pragma unroll
    for (int h=0; h<2; h++){
      int rr = r + h*64;
      float4 av = *(const float4*)(A  + (size_t)(m0+rr)*K + k0 + c4*4);
      float4 bv = *(const float4*)(Wz + (size_t)(n0+rr)*K + k0 + c4*4);
      As[c4*4+0][rr]=av.x; As[c4*4+1][rr]=av.y; As[c4*4+2][rr]=av.z; As[c4*4+3][rr]=av.w;
      Bs[c4*4+0][rr]=bv.x; Bs[c4*4+1][rr]=bv.y; Bs[c4*4+2][rr]=bv.z; Bs[c4*4+3][rr]=bv.w;
    }
    __syncthreads();
#pragma unroll
    for (int kk=0; kk<16; kk++){
      float a[8], bb[8];
      *(float4*)&a[0]  = *(const float4*)&As[kk][ty*8];
      *(float4*)&a[4]  = *(const float4*)&As[kk][ty*8+4];
      *(float4*)&bb[0] = *(const float4*)&Bs[kk][tx*8];
      *(float4*)&bb[4] = *(const float4*)&Bs[kk][tx*8+4];
#pragma unroll
      for (int i=0;i<8;i++)
#pragma unroll
        for (int j=0;j<8;j++)
          acc[i][j] = fmaf(a[i], bb[j], acc[i][j]);
    }
    __syncthreads();
  }
  float bb1[8];
#pragma unroll
  for (int j=0;j<8;j++){
    int n = n0 + tx*8 + j;
    bb1[j] = b1z[n] + (b2z ? b2z[n] : 0.f);
  }
#pragma unroll
  for (int i=0;i<8;i++){
    int m = m0 + ty*8 + i;
    float o[8];
#pragma unroll
    for (int j=0;j<8;j++) o[j] = acc[i][j] + bb1[j];
    *(float4*)(Cz + (size_t)m*ldc + n0 + tx*8)     = *(const float4*)&o[0];
    *(float4*)(Cz + (size_t)m*ldc + n0 + tx*8 + 4) = *(const float4*)&o[4];
  }
}

// ---------------- f16-dot2 GEMM for the xg projections ----------------
__global__ __launch_bounds__(256) void k_gemmh(
    const float* __restrict__ A, const uint4* __restrict__ WhT,
    float* __restrict__ C, const float* __restrict__ b1, const float* __restrict__ b2,
    int K, int ldc, size_t sW, size_t sC, int sB)
{
  int m0 = blockIdx.x * 128, n0 = blockIdx.y * 128, z = blockIdx.z;
  const uint4* Wz = WhT + (size_t)z*sW;        // sW in uint4 units = (K/8)*1024
  float* Cz = C + (size_t)z*sC;
  const float* b1z = b1 + (size_t)z*sB;
  const float* b2z = b2 ? (b2 + (size_t)z*sB) : nullptr;
  __shared__ __align__(16) unsigned Ash[8][132];   // [kpair][m]
  __shared__ __align__(16) unsigned Bsh[8][132];   // [kpair][n]
  int tid = threadIdx.x;
  int tx = tid & 15, ty = tid >> 4;
  int r = tid >> 2, c4 = tid & 3;
  int nB = tid >> 1, hhB = tid & 1;                // B stage: 128 rows x 2 j8-groups
  float acc[8][8] = {};
  for (int k0=0; k0<K; k0+=16){
#pragma unroll
    for (int h=0; h<2; h++){
      int rr = r + h*64;
      float4 av = *(const float4*)(A + (size_t)(m0+rr)*K + k0 + c4*4);
      Ash[c4*2  ][rr] = pkh2(av.x, av.y);
      Ash[c4*2+1][rr] = pkh2(av.z, av.w);
    }
    {
      uint4 wv = Wz[(size_t)(k0/8 + hhB)*1024 + n0 + nB];
      Bsh[hhB*4+0][nB] = wv.x; Bsh[hhB*4+1][nB] = wv.y;
      Bsh[hhB*4+2][nB] = wv.z; Bsh[hhB*4+3][nB] = wv.w;
    }
    __syncthreads();
#pragma unroll
    for (int kk2=0; kk2<8; kk2++){
      uint4 au0 = *(const uint4*)&Ash[kk2][ty*8];
      uint4 au1 = *(const uint4*)&Ash[kk2][ty*8+4];
      uint4 bu0 = *(const uint4*)&Bsh[kk2][tx*8];
      uint4 bu1 = *(const uint4*)&Bsh[kk2][tx*8+4];
      unsigned au[8] = {au0.x,au0.y,au0.z,au0.w,au1.x,au1.y,au1.z,au1.w};
      unsigned bu[8] = {bu0.x,bu0.y,bu0.z,bu0.w,bu1.x,bu1.y,bu1.z,bu1.w};
#pragma unroll
      for (int i=0;i<8;i++)
#pragma unroll
        for (int j=0;j<8;j++)
          acc[i][j] = dot2f(au[i], bu[j], acc[i][j]);
    }
    __syncthreads();
  }
  float bb1[8];
#pragma unroll
  for (int j=0;j<8;j++){
    int n = n0 + tx*8 + j;
    bb1[j] = b1z[n] + (b2z ? b2z[n] : 0.f);
  }
#pragma unroll
  for (int i=0;i<8;i++){
    int m = m0 + ty*8 + i;
    float o[8];
#pragma unroll
    for (int j=0;j<8;j++) o[j] = acc[i][j] + bb1[j];
    *(float4*)(Cz + (size_t)m*ldc + n0 + tx*8)     = *(const float4*)&o[0];
    *(float4*)(Cz + (size_t)m*ldc + n0 + tx*8 + 4) = *(const float4*)&o[4];
  }
}

// ---------------- dec2: recurrent, block = (dir, batch), 16 waves ----------------
// amdgpu_waves_per_eu(4,4): R8->R9 non-dec1g delta (-41 us) indicates this
// unlocked wpre[20]'s registers. Unchanged this round (control).
__global__ __launch_bounds__(1024) __attribute__((amdgpu_waves_per_eu(4,4)))
void k_rec2(
    const float* __restrict__ xg,   // [2][64][60][1024]
    const uint4* __restrict__ wT,   // [2][32][1024] f16x8
    float* __restrict__ out)        // [64][60][512]
{
  int b = blockIdx.x, d = blockIdx.y, tid = threadIdx.x;
  __shared__ __align__(16) unsigned h2pk[128];  // h packed f16x2
  __shared__ float gls[1024];
  float c = 0.f;
  if (tid < 128) h2pk[tid] = 0u;
  const uint4* wp = wT + (size_t)d*32*1024;
  uint4 wpre[20];
#pragma unroll
  for (int j=0;j<20;j++) wpre[j] = wp[j*1024 + tid];   // once, not per step
  const float* xp = xg + (((size_t)d*64 + b)*60)*1024;
  __syncthreads();
  for (int step=0; step<TDEC; step++){
    int t = d ? (TDEC-1-step) : step;
    float g = xp[(size_t)t*1024 + tid];
#pragma unroll
    for (int j8=0;j8<20;j8++){                          // register-resident part
      uint4 hv = *(const uint4*)&h2pk[j8*4];
      DOT8(g, wpre[j8], hv)
    }
#pragma unroll 4
    for (int j8=20;j8<32;j8++){                         // streamed part
      uint4 wv = wp[j8*1024 + tid];
      uint4 hv = *(const uint4*)&h2pk[j8*4];
      DOT8(g, wv, hv)
    }
    gls[tid] = g;
    __syncthreads();
    if (tid < 256){
      float ii = sigf(gls[tid]);
      float ff = sigf(gls[256+tid]);
      float gg = tanhf(gls[512+tid]);
      float oo = sigf(gls[768+tid]);
      c = fmaf(ff, c, ii*gg);
      float hn = oo * tanhf(c);
      float ho = __shfl_xor(hn, 1);
      if (!(tid&1)) h2pk[tid>>1] = pkh2(hn, ho);
      out[((size_t)b*60 + t)*512 + d*256 + tid] = hn;
    }
    __syncthreads();
  }
}

extern "C" void kernel_launch(void* const* d_in, const int* in_sizes, int n_in,
                              void* d_out, int out_size, void* d_ws, size_t ws_size,
                              hipStream_t stream) {
  const float* x      = (const float*)d_in[0];
  const float* cw1    = (const float*)d_in[1];
  const float* cb1    = (const float*)d_in[2];
  const float* cw2    = (const float*)d_in[3];
  const float* cb2    = (const float*)d_in[4];
  const float* cw3    = (const float*)d_in[5];
  const float* cb3    = (const float*)d_in[6];
  const float* attn_w = (const float*)d_in[7];
  // d_in[8] attn_b: constant over softmax axis -> drops out analytically
  const float* d1_wih = (const float*)d_in[9];
  const float* d1_whh = (const float*)d_in[10];
  const float* d1_bih = (const float*)d_in[11];
  const float* d1_bhh = (const float*)d_in[12];
  const float* w2_ih0 = (const float*)d_in[13];
  const float* w2_hh0 = (const float*)d_in[14];
  const float* b2_ih0 = (const float*)d_in[15];
  const float* b2_hh0 = (const float*)d_in[16];
  const float* w2_ih1 = (const float*)d_in[17];
  const float* w2_hh1 = (const float*)d_in[18];
  const float* b2_ih1 = (const float*)d_in[19];
  const float* b2_hh1 = (const float*)d_in[20];
  const float* out_w  = (const float*)d_in[21];
  const float* out_b  = (const float*)d_in[22];

  char* ws = (char*)d_ws;
  size_t off = 0;
  // enc region: u8 enc (8.34 MB) + rowscales (1.04 MB). Dead after dec1g —
  // reused for the dec2 weight packs (6.3 MB), packed AFTER dec1g completes.
  uint4* encq = (uint4*)(ws + off);                                // [B][L3C][2] uint4
  float* encs = (float*)(ws + off + 8338432);                      // [B][L3C]
  uint4* wih0T = (uint4*)(ws + 0);                                 // 2 MB
  uint4* wih1T = (uint4*)(ws + 2097152);                           // 2 MB
  uint4* whh0T = (uint4*)(ws + 4194304);                           // 1 MB
  uint4* whh1T = (uint4*)(ws + 5242880);                           // 1 MB
  off += 16675840;
  size_t off_h1 = off;
  float* h1buf = (float*)(ws + off); off += 8382464;               // (B,4093,8)
  float* h2buf = (float*)(ws + off); off += 16736256;              // (B,4086,16)
  float* d2in  = (float*)(ws + off_h1);                            // reuse: (B,60,512)
  float* l0    = (float*)(ws + off_h1 + 7864320);
  float* l1    = (float*)(ws + off_h1 + 15728640);
  float* xg    = (float*)(ws + off); off += 31457280;              // [2][B][60][1024]
  // dec1 packs live INSIDE the xg region (xg written only after dec1 completes)
  uint4* d1whhT = (uint4*)xg;                                      // 1 MB
  uint4* d1wihT = (uint4*)((char*)xg + 1048576);                   // +128 KB
  (void)ws_size; (void)in_sizes; (void)n_in; (void)out_size;

  // dec1 weight packs (before dec1; clobbered later by xg — fine)
  k_packwh<<<256,256,0,stream>>>(d1_whh, d1whhT, 256);
  k_packwh<<<32, 256,0,stream>>>(d1_wih, d1wihT, 32);

  k_convL<64,8,4,65><<<dim3(16,B_),256,0,stream>>>(x, cw1, cb1, h1buf, 4096, L1C);
  k_convL<8,16,8,9><<<dim3(16,B_),256,0,stream>>>(h1buf, cw2, cb2, h2buf, L1C, L2C);
  k_conv3qL<<<dim3(16,B_),256,0,stream>>>(h2buf, cw3, cb3, encq, encs, L2C, L3C);

  // dec1: 128 independent blocks (b,d); enc u8 in LDS; fused score+gate stream
  k_dec1g<<<dim3(64,2),1024,0,stream>>>(encq, encs, attn_w, d1wihT, d1whhT,
                                        d1_bih, d1_bhh, d2in);

  // dec2 weight packs into the (now dead) enc region
  k_packwh<<<512,256,0,stream>>>(w2_ih0, wih0T, 512);
  k_packwh<<<512,256,0,stream>>>(w2_ih1, wih1T, 512);
  k_packwh<<<256,256,0,stream>>>(w2_hh0, whh0T, 256);
  k_packwh<<<256,256,0,stream>>>(w2_hh1, whh1T, 256);

  // dec2 layer 0 (f16-dot2 xg GEMM)
  k_gemmh<<<dim3(30,8,2),256,0,stream>>>(d2in, wih0T, xg, b2_ih0, b2_hh0,
                                         512, 1024, (size_t)64*1024, (size_t)3840*1024, 1024);
  k_rec2<<<dim3(64,2),1024,0,stream>>>(xg, whh0T, l0);
  // dec2 layer 1
  k_gemmh<<<dim3(30,8,2),256,0,stream>>>(l0, wih1T, xg, b2_ih1, b2_hh1,
                                         512, 1024, (size_t)64*1024, (size_t)3840*1024, 1024);
  k_rec2<<<dim3(64,2),1024,0,stream>>>(xg, whh1T, l1);
  // output projection (fp32 — final output precision)
  k_gemm<<<dim3(30,1,1),256,0,stream>>>(l1, out_w, (float*)d_out, out_b, nullptr,
                                        512, 128, 0, 0, 0);
}

// Round 15
// 1762.443 us; speedup vs baseline: 1.3573x; 1.3573x over previous
//
#include <hip/hip_runtime.h>

#define B_    64
#define L1C   4093
#define L2C   4086
#define L3C   4071
#define TDEC  60

static __device__ __forceinline__ float sigf(float x){ return 1.f/(1.f + __expf(-x)); }

// ---------------- f16 pack / dot helpers ----------------
typedef _Float16 h2_t __attribute__((ext_vector_type(2)));
union U2H { unsigned u; h2_t h; };

static __device__ __forceinline__ unsigned pkh2(float a, float b){
  U2H r; r.h[0] = (_Float16)a; r.h[1] = (_Float16)b; return r.u;
}
// acc += dot(w_half2, h_half2) in fp32 — v_dot2_f32_f16 (full-rate VOP3P)
static __device__ __forceinline__ float dot2f(unsigned w, unsigned h, float acc){
  U2H a; a.u = w; U2H b; b.u = h;
#if __has_builtin(__builtin_amdgcn_fdot2)
  return __builtin_amdgcn_fdot2(a.h, b.h, acc, false);
#else
  acc = fmaf((float)a.h[0], (float)b.h[0], acc);
  acc = fmaf((float)a.h[1], (float)b.h[1], acc);
  return acc;
#endif
}

// 8 MACs from one uint4 of packed f16 weights x one uint4 of packed f16 h
#define DOT8(g, wv, hv) \
  g = dot2f(wv.x, hv.x, g); g = dot2f(wv.y, hv.y, g); \
  g = dot2f(wv.z, hv.z, g); g = dot2f(wv.w, hv.w, g);

// DPP-fused add: x + dpp_perm(x). VALU-pipe, replaces ds_swizzle shuffles.
// 0xB1 = quad_perm xor1, 0x4E = quad_perm xor2, 0x124/0x128 = row_ror:4/8.
template<int CTRL>
static __device__ __forceinline__ float dppadd(float x){
  int y = __builtin_amdgcn_update_dpp(0, __float_as_int(x), CTRL, 0xf, 0xf, true);
  return x + __int_as_float(y);
}

// ---------------- convs: LDS-staged input (coalesced), scalar fmaf ----------------
template<int CIN,int COUT,int KW,int CINP>
__global__ __launch_bounds__(256) void k_convL(
    const float* __restrict__ in, const float* __restrict__ w,
    const float* __restrict__ bias, float* __restrict__ outp,
    int Lin_, int Lout_)
{
  __shared__ float xs[(256+KW-1)*CINP];
  int bi = blockIdx.y, l0 = blockIdx.x*256, tid = threadIdx.x;
  int nrow = min(256+KW-1, Lin_-l0);
  const float* ip = in + ((size_t)bi*Lin_ + l0)*CIN;
  for (int i = tid; i < nrow*(CIN/4); i += 256){
    int rr = i/(CIN/4), cc = i - rr*(CIN/4);
    float4 v = *(const float4*)(ip + rr*CIN + cc*4);
    float* dst = &xs[rr*CINP + cc*4];
    dst[0]=v.x; dst[1]=v.y; dst[2]=v.z; dst[3]=v.w;
  }
  __syncthreads();
  int l = l0 + tid;
  if (l >= Lout_) return;
  float acc[COUT];
#pragma unroll
  for (int o=0;o<COUT;o++) acc[o] = bias[o];
  for (int k=0;k<KW;k++){
    const float* xr = &xs[(tid+k)*CINP];
#pragma unroll
    for (int i=0;i<CIN;i++){
      float xv = xr[i];
#pragma unroll
      for (int o=0;o<COUT;o++)
        acc[o] = fmaf(xv, w[(o*CIN + i)*KW + k], acc[o]);
    }
  }
  float* op = outp + ((size_t)bi*Lout_ + l)*COUT;
#pragma unroll
  for (int o=0;o<COUT;o++) op[o] = fmaxf(acc[o], 0.f);
}

// conv3: LDS-staged + scalar fmaf + relu + row-quantize to u8 (scale = rowmax/255)
__global__ __launch_bounds__(256) void k_conv3qL(
    const float* __restrict__ in, const float* __restrict__ w,
    const float* __restrict__ bias, uint4* __restrict__ encq,
    float* __restrict__ encs, int Lin_, int Lout_)
{
  __shared__ float xs[(256+15)*17];
  int bi = blockIdx.y, l0 = blockIdx.x*256, tid = threadIdx.x;
  int nrow = min(256+15, Lin_-l0);
  const float* ip = in + ((size_t)bi*Lin_ + l0)*16;
  for (int i = tid; i < nrow*4; i += 256){
    int rr = i>>2, cc = i&3;
    float4 v = *(const float4*)(ip + rr*16 + cc*4);
    float* dst = &xs[rr*17 + cc*4];
    dst[0]=v.x; dst[1]=v.y; dst[2]=v.z; dst[3]=v.w;
  }
  __syncthreads();
  int l = l0 + tid;
  if (l >= Lout_) return;
  float acc[32];
#pragma unroll
  for (int o=0;o<32;o++) acc[o] = bias[o];
  for (int k=0;k<16;k++){
    const float* xr = &xs[(tid+k)*17];
#pragma unroll
    for (int i=0;i<16;i++){
      float xv = xr[i];
#pragma unroll
      for (int o=0;o<32;o++)
        acc[o] = fmaf(xv, w[(o*16 + i)*16 + k], acc[o]);
    }
  }
  float mx = 0.f;
#pragma unroll
  for (int o=0;o<32;o++){ acc[o] = fmaxf(acc[o],0.f); mx = fmaxf(mx, acc[o]); }
  float scale = mx * (1.f/255.f);
  float inv = (mx > 0.f) ? (255.f/mx) : 0.f;
  unsigned qs[8];
#pragma unroll
  for (int q8=0;q8<8;q8++){
    unsigned q0 = (unsigned)(acc[q8*4+0]*inv + 0.5f);
    unsigned q1 = (unsigned)(acc[q8*4+1]*inv + 0.5f);
    unsigned q2 = (unsigned)(acc[q8*4+2]*inv + 0.5f);
    unsigned q3 = (unsigned)(acc[q8*4+3]*inv + 0.5f);
    qs[q8] = q0 | (q1<<8) | (q2<<16) | (q3<<24);
  }
  uint4* op = encq + ((size_t)bi*Lout_ + l)*2;
  op[0] = make_uint4(qs[0],qs[1],qs[2],qs[3]);
  op[1] = make_uint4(qs[4],qs[5],qs[6],qs[7]);
  encs[(size_t)bi*Lout_ + l] = scale;
}

// ---------------- pack weights: [2][1024][K] fp32 -> [2][K/8][1024] f16x8 ----------------
__global__ __launch_bounds__(256) void k_packwh(
    const float* __restrict__ w, uint4* __restrict__ wT, int K)
{
  int gid = blockIdx.x*256 + threadIdx.x;
  int per = (K/8)*1024;
  int d = gid / per, rem = gid - d*per;
  int j8 = rem >> 10, row = rem & 1023;
  const float* src = w + ((size_t)d*1024 + row)*K + j8*8;
  float4 a = *(const float4*)src;
  float4 b = *(const float4*)(src+4);
  uint4 o;
  o.x = pkh2(a.x, a.y);
  o.y = pkh2(a.z, a.w);
  o.z = pkh2(b.x, b.y);
  o.w = pkh2(b.z, b.w);
  wT[gid] = o;
}

#define CVT8(r, qv) \
  r[0]=(float)( qv.x      & 255u); r[1]=(float)((qv.x>>8 ) & 255u); \
  r[2]=(float)((qv.x>>16) & 255u); r[3]=(float)((qv.x>>24)       ); \
  r[4]=(float)( qv.y      & 255u); r[5]=(float)((qv.y>>8 ) & 255u); \
  r[6]=(float)((qv.y>>16) & 255u); r[7]=(float)((qv.y>>24)       );

// ---------------- dec1: block=(b,d); enc u8 in LDS; quad split (8ch/thread) ----------------
// FINAL streamed form (R6/R9-measured, 483 us). Register preload of whh is
// impossible: the allocator pins 1024-thread kernels to 64 VGPR; neither
// __launch_bounds__(,4) (R8) nor amdgpu_waves_per_eu(4,4) (R11) raises it —
// preload arrays spill to scratch (R7: 3.1GB, R11: 1.2GB FETCH). Do not retry.
__global__ __launch_bounds__(1024) void k_dec1g(
    const uint4* __restrict__ encq,        // [B][L3C][2] uint4 (32 x u8)
    const float* __restrict__ encs,        // [B][L3C] rowscale
    const float* __restrict__ attn_w,      // [256][32]
    const uint4* __restrict__ wihT,        // [2][4][1024] f16x8 (K=32)
    const uint4* __restrict__ whhT,        // [2][32][1024] f16x8 (K=256)
    const float* __restrict__ bih, const float* __restrict__ bhh,
    float* __restrict__ d2in)              // [B][60][512]
{
  int b = blockIdx.x, d = blockIdx.y, tid = threadIdx.x;
  int c = tid & 3, rb = tid >> 2;          // quad covers rows rb+256k, k=0..15; lane owns ch c*8..c*8+7

  __shared__ __align__(16) uint2 encQ2[16384];  // 128 KB: row l = 4 uint2 (32 x u8)
  __shared__ float sls[4096];                   // 16 KB rowscales
  __shared__ __align__(16) float hls[256];      // fp32 h (attention matvec input)
  __shared__ __align__(16) unsigned h2pk[128];  // h packed f16x2 (gate dot input)
  __shared__ __align__(16) unsigned ctxh[16];   // ctx packed f16x2
  __shared__ float vl[32];
  __shared__ float maxenc[32];
  __shared__ float Msh;
  __shared__ float red[1024];
  __shared__ float scr[512];                    // [16 waves][32 ch]
  __shared__ float gls[1024];

  { // stage enc slice once (uint4-coalesced)
    const uint4* src = encq + (size_t)b*L3C*2;
    uint4* dst = (uint4*)encQ2;
    for (int i = tid; i < 8192; i += 1024)
      dst[i] = (i < L3C*2) ? src[i] : make_uint4(0,0,0,0);
    const float* ss = encs + (size_t)b*L3C;
    for (int i = tid; i < 4096; i += 1024)
      sls[i] = (i < L3C) ? ss[i] : 0.f;
  }
  if (tid < 256) hls[tid] = 0.f;
  if (tid < 128) h2pk[tid] = 0u;
  float creg = 0.f;
  float bsum = bih[(size_t)d*1024 + tid] + bhh[(size_t)d*1024 + tid];
  const uint4* whp = whhT + (size_t)d*32768;
  __syncthreads();

  { // one-time: per-channel max of real enc (>=0) -> maxenc[32]
    float mc[8];
#pragma unroll
    for (int j=0;j<8;j++) mc[j] = 0.f;
#pragma unroll
    for (int k=0;k<16;k++){
      int l = rb + 256*k;
      uint2 qv = encQ2[l*4 + c];
      float sl = sls[l];
      float r[8]; CVT8(r, qv)
#pragma unroll
      for (int j=0;j<8;j++) mc[j] = fmaxf(mc[j], r[j]*sl);
    }
#pragma unroll
    for (int off=4; off<=32; off<<=1){
#pragma unroll
      for (int j=0;j<8;j++) mc[j] = fmaxf(mc[j], __shfl_xor(mc[j], off));
    }
    int wid = tid >> 6;
    if ((tid&63) < 4){
#pragma unroll
      for (int j=0;j<8;j++) scr[wid*32 + c*8 + j] = mc[j];
    }
    __syncthreads();
    if (tid < 32){
      float mm = 0.f;
#pragma unroll
      for (int w=0;w<16;w++) mm = fmaxf(mm, scr[w*32 + tid]);
      maxenc[tid] = mm;
    }
    __syncthreads();
  }

  for (int t=0; t<TDEC; t++){
    // -- phase 1: v[c] = sum_u h[u]*attn_w[u][c]; M = sum_c maxenc[c]*max(v,0) --
    {
      int cc = tid & 31, part = tid >> 5;
      const float* wp = attn_w + (size_t)(part*8)*32 + cc;
      float s = 0.f;
#pragma unroll
      for (int k=0;k<8;k++) s = fmaf(hls[part*8+k], wp[k*32], s);
      red[tid] = s;
    }
    __syncthreads();
    if (tid < 32){
      float v = 0.f;
#pragma unroll
      for (int q=0;q<32;q++) v += red[q*32 + tid];
      vl[tid] = v;
      float mt = maxenc[tid] * fmaxf(v, 0.f);
#pragma unroll
      for (int off=1; off<32; off<<=1) mt += __shfl_xor(mt, off);
      if (tid==0) Msh = mt;
    }
    __syncthreads();

    // -- fused phase 2 (enc scoring, static-bound softmax) + whh·h gate stream --
    float vreg[8];
#pragma unroll
    for (int j=0;j<8;j++) vreg[j] = vl[c*8 + j];
    float M = Msh;
    float ssum = 0.f;
    float acc[8];
#pragma unroll
    for (int j=0;j<8;j++) acc[j] = 0.f;
    float g = bsum;                          // whh dots accumulate here (h stable this step)
#pragma unroll 4
    for (int k=0;k<16;k++){
      uint4 wv0 = whp[(2*k  )*1024 + tid];   // whh stream overlapped with scoring
      uint4 wv1 = whp[(2*k+1)*1024 + tid];
      int l = rb + 256*k;
      uint2 qv = encQ2[l*4 + c];
      float sl = sls[l];
      float r[8]; CVT8(r, qv)
      float s = 0.f;
#pragma unroll
      for (int j=0;j<8;j++) s = fmaf(r[j], vreg[j], s);
      s = dppadd<0xB1>(s);                   // quad xor1 (VALU)
      s = dppadd<0x4E>(s);                   // quad xor2 (VALU)
      s *= sl;
      if (l >= L3C) s = -3.0e38f;            // pad rows (only k=15 can trigger)
      float e = __expf(s - M);
      ssum += e;
      float em = e * sl;
#pragma unroll
      for (int j=0;j<8;j++) acc[j] = fmaf(em, r[j], acc[j]);
      uint4 hv0 = *(const uint4*)&h2pk[(2*k  )*4];
      uint4 hv1 = *(const uint4*)&h2pk[(2*k+1)*4];
      DOT8(g, wv0, hv0)
      DOT8(g, wv1, hv1)
    }
    // reduce across quads: row_ror4+ror8 (VALU) then xor16/xor32 (cross-row)
    ssum = dppadd<0x124>(ssum); ssum = dppadd<0x128>(ssum);
    ssum += __shfl_xor(ssum, 16); ssum += __shfl_xor(ssum, 32);
#pragma unroll
    for (int j=0;j<8;j++){
      acc[j] = dppadd<0x124>(acc[j]); acc[j] = dppadd<0x128>(acc[j]);
      acc[j] += __shfl_xor(acc[j], 16); acc[j] += __shfl_xor(acc[j], 32);
    }
    int wid = tid >> 6;
    if ((tid&63) < 4){
#pragma unroll
      for (int j=0;j<8;j++) scr[wid*32 + c*8 + j] = acc[j];
    }
    if ((tid&63)==0) red[wid] = ssum;
    __syncthreads();
    if (tid < 32){
      float S = 0.f, s2 = 0.f;
#pragma unroll
      for (int w=0;w<16;w++){ S += red[w]; s2 += scr[w*32 + tid]; }
      float cv = s2 / S;
      float co = __shfl_xor(cv, 1);
      if (!(tid&1)) ctxh[tid>>1] = pkh2(cv, co);
    }
    __syncthreads();

    // -- wih·ctx (K=32, streamed — cheap) + nonlinearity --
#pragma unroll
    for (int c8=0;c8<4;c8++){
      uint4 wv = wihT[(size_t)d*4096 + c8*1024 + tid];
      uint4 hv = *(const uint4*)&ctxh[c8*4];
      DOT8(g, wv, hv)
    }
    gls[tid] = g;
    __syncthreads();
    if (tid < 256){
      float ii = sigf(gls[tid]);
      float ff = sigf(gls[256+tid]);
      float gg = tanhf(gls[512+tid]);
      float oo = sigf(gls[768+tid]);
      creg = fmaf(ff, creg, ii*gg);
      float hn = oo * tanhf(creg);
      hls[tid] = hn;
      float ho = __shfl_xor(hn, 1);
      if (!(tid&1)) h2pk[tid>>1] = pkh2(hn, ho);
      int tout = d ? (59 - t) : t;
      d2in[((size_t)b*60 + tout)*512 + d*256 + tid] = hn;
    }
    __syncthreads();
  }
}

// ---------------- fp32 GEMM (out-projection only — keeps final output precision) ----------------
__global__ __launch_bounds__(256) void k_gemm(
    const float* __restrict__ A, const float* __restrict__ W,
    float* __restrict__ C, const float* __restrict__ b1, const float* __restrict__ b2,
    int K, int ldc, size_t sW, size_t sC, int sB)
{
  int m0 = blockIdx.x * 128, n0 = blockIdx.y * 128, z = blockIdx.z;
  const float* Wz = W + (size_t)z*sW;
  float* Cz = C + (size_t)z*sC;
  const float* b1z = b1 + (size_t)z*sB;
  const float* b2z = b2 ? (b2 + (size_t)z*sB) : nullptr;
  __shared__ __align__(16) float As[16][132];
  __shared__ __align__(16) float Bs[16][132];
  int tid = threadIdx.x;
  int tx = tid & 15, ty = tid >> 4;
  int r = tid >> 2, c4 = tid & 3;
  float acc[8][8] = {};
  for (int k0=0; k0<K; k0+=16){
#pragma unroll
    for (int h=0; h<2; h++){
      int rr = r + h*64;
      float4 av = *(const float4*)(A  + (size_t)(m0+rr)*K + k0 + c4*4);
      float4 bv = *(const float4*)(Wz + (size_t)(n0+rr)*K + k0 + c4*4);
      As[c4*4+0][rr]=av.x; As[c4*4+1][rr]=av.y; As[c4*4+2][rr]=av.z; As[c4*4+3][rr]=av.w;
      Bs[c4*4+0][rr]=bv.x; Bs[c4*4+1][rr]=bv.y; Bs[c4*4+2][rr]=bv.z; Bs[c4*4+3][rr]=bv.w;
    }
    __syncthreads();
#pragma unroll
    for (int kk=0; kk<16; kk++){
      float a[8], bb[8];
      *(float4*)&a[0]  = *(const float4*)&As[kk][ty*8];
      *(float4*)&a[4]  = *(const float4*)&As[kk][ty*8+4];
      *(float4*)&bb[0] = *(const float4*)&Bs[kk][tx*8];
      *(float4*)&bb[4] = *(const float4*)&Bs[kk][tx*8+4];
#pragma unroll
      for (int i=0;i<8;i++)
#pragma unroll
        for (int j=0;j<8;j++)
          acc[i][j] = fmaf(a[i], bb[j], acc[i][j]);
    }
    __syncthreads();
  }
  float bb1[8];
#pragma unroll
  for (int j=0;j<8;j++){
    int n = n0 + tx*8 + j;
    bb1[j] = b1z[n] + (b2z ? b2z[n] : 0.f);
  }
#pragma unroll
  for (int i=0;i<8;i++){
    int m = m0 + ty*8 + i;
    float o[8];
#pragma unroll
    for (int j=0;j<8;j++) o[j] = acc[i][j] + bb1[j];
    *(float4*)(Cz + (size_t)m*ldc + n0 + tx*8)     = *(const float4*)&o[0];
    *(float4*)(Cz + (size_t)m*ldc + n0 + tx*8 + 4) = *(const float4*)&o[4];
  }
}

// ---------------- f16-dot2 GEMM for the xg projections ----------------
__global__ __launch_bounds__(256) void k_gemmh(
    const float* __restrict__ A, const uint4* __restrict__ WhT,
    float* __restrict__ C, const float* __restrict__ b1, const float* __restrict__ b2,
    int K, int ldc, size_t sW, size_t sC, int sB)
{
  int m0 = blockIdx.x * 128, n0 = blockIdx.y * 128, z = blockIdx.z;
  const uint4* Wz = WhT + (size_t)z*sW;        // sW in uint4 units = (K/8)*1024
  float* Cz = C + (size_t)z*sC;
  const float* b1z = b1 + (size_t)z*sB;
  const float* b2z = b2 ? (b2 + (size_t)z*sB) : nullptr;
  __shared__ __align__(16) unsigned Ash[8][132];   // [kpair][m]
  __shared__ __align__(16) unsigned Bsh[8][132];   // [kpair][n]
  int tid = threadIdx.x;
  int tx = tid & 15, ty = tid >> 4;
  int r = tid >> 2, c4 = tid & 3;
  int nB = tid >> 1, hhB = tid & 1;                // B stage: 128 rows x 2 j8-groups
  float acc[8][8] = {};
  for (int k0=0; k0<K; k0+=16){
#pragma unroll
    for (int h=0; h<2; h++){
      int rr = r + h*64;
      float4 av = *(const float4*)(A + (size_t)(m0+rr)*K + k0 + c4*4);
      Ash[c4*2  ][rr] = pkh2(av.x, av.y);
      Ash[c4*2+1][rr] = pkh2(av.z, av.w);
    }
    {
      uint4 wv = Wz[(size_t)(k0/8 + hhB)*1024 + n0 + nB];
      Bsh[hhB*4+0][nB] = wv.x; Bsh[hhB*4+1][nB] = wv.y;
      Bsh[hhB*4+2][nB] = wv.z; Bsh[hhB*4+3][nB] = wv.w;
    }
    __syncthreads();
#pragma unroll
    for (int kk2=0; kk2<8; kk2++){
      uint4 au0 = *(const uint4*)&Ash[kk2][ty*8];
      uint4 au1 = *(const uint4*)&Ash[kk2][ty*8+4];
      uint4 bu0 = *(const uint4*)&Bsh[kk2][tx*8];
      uint4 bu1 = *(const uint4*)&Bsh[kk2][tx*8+4];
      unsigned au[8] = {au0.x,au0.y,au0.z,au0.w,au1.x,au1.y,au1.z,au1.w};
      unsigned bu[8] = {bu0.x,bu0.y,bu0.z,bu0.w,bu1.x,bu1.y,bu1.z,bu1.w};
#pragma unroll
      for (int i=0;i<8;i++)
#pragma unroll
        for (int j=0;j<8;j++)
          acc[i][j] = dot2f(au[i], bu[j], acc[i][j]);
    }
    __syncthreads();
  }
  float bb1[8];
#pragma unroll
  for (int j=0;j<8;j++){
    int n = n0 + tx*8 + j;
    bb1[j] = b1z[n] + (b2z ? b2z[n] : 0.f);
  }
#pragma unroll
  for (int i=0;i<8;i++){
    int m = m0 + ty*8 + i;
    float o[8];
#pragma unroll
    for (int j=0;j<8;j++) o[j] = acc[i][j] + bb1[j];
    *(float4*)(Cz + (size_t)m*ldc + n0 + tx*8)     = *(const float4*)&o[0];
    *(float4*)(Cz + (size_t)m*ldc + n0 + tx*8 + 4) = *(const float4*)&o[4];
  }
}

// ---------------- dec2: recurrent, block = (dir, batch), 16 waves ----------------
// Pure streamed (preload + waves_per_eu attribute REMOVED): under the proven
// 64-VGPR pin, the preload was at best rematerialized into these same streamed
// loads. This round isolates its contribution (prediction: neutral, ±40us).
__global__ __launch_bounds__(1024) void k_rec2(
    const float* __restrict__ xg,   // [2][64][60][1024]
    const uint4* __restrict__ wT,   // [2][32][1024] f16x8
    float* __restrict__ out)        // [64][60][512]
{
  int b = blockIdx.x, d = blockIdx.y, tid = threadIdx.x;
  __shared__ __align__(16) unsigned h2pk[128];  // h packed f16x2
  __shared__ float gls[1024];
  float c = 0.f;
  if (tid < 128) h2pk[tid] = 0u;
  const uint4* wp = wT + (size_t)d*32*1024;
  const float* xp = xg + (((size_t)d*64 + b)*60)*1024;
  __syncthreads();
  for (int step=0; step<TDEC; step++){
    int t = d ? (TDEC-1-step) : step;
    float g = xp[(size_t)t*1024 + tid];
#pragma unroll 4
    for (int j8=0;j8<32;j8++){
      uint4 wv = wp[j8*1024 + tid];
      uint4 hv = *(const uint4*)&h2pk[j8*4];
      DOT8(g, wv, hv)
    }
    gls[tid] = g;
    __syncthreads();
    if (tid < 256){
      float ii = sigf(gls[tid]);
      float ff = sigf(gls[256+tid]);
      float gg = tanhf(gls[512+tid]);
      float oo = sigf(gls[768+tid]);
      c = fmaf(ff, c, ii*gg);
      float hn = oo * tanhf(c);
      float ho = __shfl_xor(hn, 1);
      if (!(tid&1)) h2pk[tid>>1] = pkh2(hn, ho);
      out[((size_t)b*60 + t)*512 + d*256 + tid] = hn;
    }
    __syncthreads();
  }
}

extern "C" void kernel_launch(void* const* d_in, const int* in_sizes, int n_in,
                              void* d_out, int out_size, void* d_ws, size_t ws_size,
                              hipStream_t stream) {
  const float* x      = (const float*)d_in[0];
  const float* cw1    = (const float*)d_in[1];
  const float* cb1    = (const float*)d_in[2];
  const float* cw2    = (const float*)d_in[3];
  const float* cb2    = (const float*)d_in[4];
  const float* cw3    = (const float*)d_in[5];
  const float* cb3    = (const float*)d_in[6];
  const float* attn_w = (const float*)d_in[7];
  // d_in[8] attn_b: constant over softmax axis -> drops out analytically
  const float* d1_wih = (const float*)d_in[9];
  const float* d1_whh = (const float*)d_in[10];
  const float* d1_bih = (const float*)d_in[11];
  const float* d1_bhh = (const float*)d_in[12];
  const float* w2_ih0 = (const float*)d_in[13];
  const float* w2_hh0 = (const float*)d_in[14];
  const float* b2_ih0 = (const float*)d_in[15];
  const float* b2_hh0 = (const float*)d_in[16];
  const float* w2_ih1 = (const float*)d_in[17];
  const float* w2_hh1 = (const float*)d_in[18];
  const float* b2_ih1 = (const float*)d_in[19];
  const float* b2_hh1 = (const float*)d_in[20];
  const float* out_w  = (const float*)d_in[21];
  const float* out_b  = (const float*)d_in[22];

  char* ws = (char*)d_ws;
  size_t off = 0;
  // enc region: u8 enc (8.34 MB) + rowscales (1.04 MB). Dead after dec1g —
  // reused for the dec2 weight packs (6.3 MB), packed AFTER dec1g completes.
  uint4* encq = (uint4*)(ws + off);                                // [B][L3C][2] uint4
  float* encs = (float*)(ws + off + 8338432);                      // [B][L3C]
  uint4* wih0T = (uint4*)(ws + 0);                                 // 2 MB
  uint4* wih1T = (uint4*)(ws + 2097152);                           // 2 MB
  uint4* whh0T = (uint4*)(ws + 4194304);                           // 1 MB
  uint4* whh1T = (uint4*)(ws + 5242880);                           // 1 MB
  off += 16675840;
  size_t off_h1 = off;
  float* h1buf = (float*)(ws + off); off += 8382464;               // (B,4093,8)
  float* h2buf = (float*)(ws + off); off += 16736256;              // (B,4086,16)
  float* d2in  = (float*)(ws + off_h1);                            // reuse: (B,60,512)
  float* l0    = (float*)(ws + off_h1 + 7864320);
  float* l1    = (float*)(ws + off_h1 + 15728640);
  float* xg    = (float*)(ws + off); off += 31457280;              // [2][B][60][1024]
  // dec1 packs live INSIDE the xg region (xg written only after dec1 completes)
  uint4* d1whhT = (uint4*)xg;                                      // 1 MB
  uint4* d1wihT = (uint4*)((char*)xg + 1048576);                   // +128 KB
  (void)ws_size; (void)in_sizes; (void)n_in; (void)out_size;

  // dec1 weight packs (before dec1; clobbered later by xg — fine)
  k_packwh<<<256,256,0,stream>>>(d1_whh, d1whhT, 256);
  k_packwh<<<32, 256,0,stream>>>(d1_wih, d1wihT, 32);

  k_convL<64,8,4,65><<<dim3(16,B_),256,0,stream>>>(x, cw1, cb1, h1buf, 4096, L1C);
  k_convL<8,16,8,9><<<dim3(16,B_),256,0,stream>>>(h1buf, cw2, cb2, h2buf, L1C, L2C);
  k_conv3qL<<<dim3(16,B_),256,0,stream>>>(h2buf, cw3, cb3, encq, encs, L2C, L3C);

  // dec1: 128 independent blocks (b,d); enc u8 in LDS; fused score+gate stream
  k_dec1g<<<dim3(64,2),1024,0,stream>>>(encq, encs, attn_w, d1wihT, d1whhT,
                                        d1_bih, d1_bhh, d2in);

  // dec2 weight packs into the (now dead) enc region
  k_packwh<<<512,256,0,stream>>>(w2_ih0, wih0T, 512);
  k_packwh<<<512,256,0,stream>>>(w2_ih1, wih1T, 512);
  k_packwh<<<256,256,0,stream>>>(w2_hh0, whh0T, 256);
  k_packwh<<<256,256,0,stream>>>(w2_hh1, whh1T, 256);

  // dec2 layer 0 (f16-dot2 xg GEMM)
  k_gemmh<<<dim3(30,8,2),256,0,stream>>>(d2in, wih0T, xg, b2_ih0, b2_hh0,
                                         512, 1024, (size_t)64*1024, (size_t)3840*1024, 1024);
  k_rec2<<<dim3(64,2),1024,0,stream>>>(xg, whh0T, l0);
  // dec2 layer 1
  k_gemmh<<<dim3(30,8,2),256,0,stream>>>(l0, wih1T, xg, b2_ih1, b2_hh1,
                                         512, 1024, (size_t)64*1024, (size_t)3840*1024, 1024);
  k_rec2<<<dim3(64,2),1024,0,stream>>>(xg, whh1T, l1);
  // output projection (fp32 — final output precision)
  k_gemm<<<dim3(30,1,1),256,0,stream>>>(l1, out_w, (float*)d_out, out_b, nullptr,
                                        512, 128, 0, 0, 0);
}

// Round 16
// 1607.187 us; speedup vs baseline: 1.4884x; 1.0966x over previous
//
#include <hip/hip_runtime.h>

#define B_    64
#define L1C   4093
#define L2C   4086
#define L3C   4071
#define TDEC  60

static __device__ __forceinline__ float sigf(float x){ return 1.f/(1.f + __expf(-x)); }

// ---------------- f16 pack / dot helpers ----------------
typedef _Float16 h2_t __attribute__((ext_vector_type(2)));
union U2H { unsigned u; h2_t h; };

static __device__ __forceinline__ unsigned pkh2(float a, float b){
  U2H r; r.h[0] = (_Float16)a; r.h[1] = (_Float16)b; return r.u;
}
// acc += dot(w_half2, h_half2) in fp32 — v_dot2_f32_f16 (full-rate VOP3P)
static __device__ __forceinline__ float dot2f(unsigned w, unsigned h, float acc){
  U2H a; a.u = w; U2H b; b.u = h;
#if __has_builtin(__builtin_amdgcn_fdot2)
  return __builtin_amdgcn_fdot2(a.h, b.h, acc, false);
#else
  acc = fmaf((float)a.h[0], (float)b.h[0], acc);
  acc = fmaf((float)a.h[1], (float)b.h[1], acc);
  return acc;
#endif
}

// 8 MACs from one uint4 of packed f16 weights x one uint4 of packed f16 h
#define DOT8(g, wv, hv) \
  g = dot2f(wv.x, hv.x, g); g = dot2f(wv.y, hv.y, g); \
  g = dot2f(wv.z, hv.z, g); g = dot2f(wv.w, hv.w, g);

// DPP-fused add: x + dpp_perm(x). VALU-pipe, replaces ds_swizzle shuffles.
// 0xB1 = quad_perm xor1, 0x4E = quad_perm xor2, 0x124/0x128 = row_ror:4/8.
template<int CTRL>
static __device__ __forceinline__ float dppadd(float x){
  int y = __builtin_amdgcn_update_dpp(0, __float_as_int(x), CTRL, 0xf, 0xf, true);
  return x + __int_as_float(y);
}

// ---------------- convs: LDS-staged input (coalesced), scalar fmaf ----------------
template<int CIN,int COUT,int KW,int CINP>
__global__ __launch_bounds__(256) void k_convL(
    const float* __restrict__ in, const float* __restrict__ w,
    const float* __restrict__ bias, float* __restrict__ outp,
    int Lin_, int Lout_)
{
  __shared__ float xs[(256+KW-1)*CINP];
  int bi = blockIdx.y, l0 = blockIdx.x*256, tid = threadIdx.x;
  int nrow = min(256+KW-1, Lin_-l0);
  const float* ip = in + ((size_t)bi*Lin_ + l0)*CIN;
  for (int i = tid; i < nrow*(CIN/4); i += 256){
    int rr = i/(CIN/4), cc = i - rr*(CIN/4);
    float4 v = *(const float4*)(ip + rr*CIN + cc*4);
    float* dst = &xs[rr*CINP + cc*4];
    dst[0]=v.x; dst[1]=v.y; dst[2]=v.z; dst[3]=v.w;
  }
  __syncthreads();
  int l = l0 + tid;
  if (l >= Lout_) return;
  float acc[COUT];
#pragma unroll
  for (int o=0;o<COUT;o++) acc[o] = bias[o];
  for (int k=0;k<KW;k++){
    const float* xr = &xs[(tid+k)*CINP];
#pragma unroll
    for (int i=0;i<CIN;i++){
      float xv = xr[i];
#pragma unroll
      for (int o=0;o<COUT;o++)
        acc[o] = fmaf(xv, w[(o*CIN + i)*KW + k], acc[o]);
    }
  }
  float* op = outp + ((size_t)bi*Lout_ + l)*COUT;
#pragma unroll
  for (int o=0;o<COUT;o++) op[o] = fmaxf(acc[o], 0.f);
}

// conv3: LDS-staged + scalar fmaf + relu + row-quantize to u8 (scale = rowmax/255)
__global__ __launch_bounds__(256) void k_conv3qL(
    const float* __restrict__ in, const float* __restrict__ w,
    const float* __restrict__ bias, uint4* __restrict__ encq,
    float* __restrict__ encs, int Lin_, int Lout_)
{
  __shared__ float xs[(256+15)*17];
  int bi = blockIdx.y, l0 = blockIdx.x*256, tid = threadIdx.x;
  int nrow = min(256+15, Lin_-l0);
  const float* ip = in + ((size_t)bi*Lin_ + l0)*16;
  for (int i = tid; i < nrow*4; i += 256){
    int rr = i>>2, cc = i&3;
    float4 v = *(const float4*)(ip + rr*16 + cc*4);
    float* dst = &xs[rr*17 + cc*4];
    dst[0]=v.x; dst[1]=v.y; dst[2]=v.z; dst[3]=v.w;
  }
  __syncthreads();
  int l = l0 + tid;
  if (l >= Lout_) return;
  float acc[32];
#pragma unroll
  for (int o=0;o<32;o++) acc[o] = bias[o];
  for (int k=0;k<16;k++){
    const float* xr = &xs[(tid+k)*17];
#pragma unroll
    for (int i=0;i<16;i++){
      float xv = xr[i];
#pragma unroll
      for (int o=0;o<32;o++)
        acc[o] = fmaf(xv, w[(o*16 + i)*16 + k], acc[o]);
    }
  }
  float mx = 0.f;
#pragma unroll
  for (int o=0;o<32;o++){ acc[o] = fmaxf(acc[o],0.f); mx = fmaxf(mx, acc[o]); }
  float scale = mx * (1.f/255.f);
  float inv = (mx > 0.f) ? (255.f/mx) : 0.f;
  unsigned qs[8];
#pragma unroll
  for (int q8=0;q8<8;q8++){
    unsigned q0 = (unsigned)(acc[q8*4+0]*inv + 0.5f);
    unsigned q1 = (unsigned)(acc[q8*4+1]*inv + 0.5f);
    unsigned q2 = (unsigned)(acc[q8*4+2]*inv + 0.5f);
    unsigned q3 = (unsigned)(acc[q8*4+3]*inv + 0.5f);
    qs[q8] = q0 | (q1<<8) | (q2<<16) | (q3<<24);
  }
  uint4* op = encq + ((size_t)bi*Lout_ + l)*2;
  op[0] = make_uint4(qs[0],qs[1],qs[2],qs[3]);
  op[1] = make_uint4(qs[4],qs[5],qs[6],qs[7]);
  encs[(size_t)bi*Lout_ + l] = scale;
}

// ---------------- pack weights: [2][1024][K] fp32 -> [2][K/8][1024] f16x8 ----------------
__global__ __launch_bounds__(256) void k_packwh(
    const float* __restrict__ w, uint4* __restrict__ wT, int K)
{
  int gid = blockIdx.x*256 + threadIdx.x;
  int per = (K/8)*1024;
  int d = gid / per, rem = gid - d*per;
  int j8 = rem >> 10, row = rem & 1023;
  const float* src = w + ((size_t)d*1024 + row)*K + j8*8;
  float4 a = *(const float4*)src;
  float4 b = *(const float4*)(src+4);
  uint4 o;
  o.x = pkh2(a.x, a.y);
  o.y = pkh2(a.z, a.w);
  o.z = pkh2(b.x, b.y);
  o.w = pkh2(b.z, b.w);
  wT[gid] = o;
}

#define CVT8(r, qv) \
  r[0]=(float)( qv.x      & 255u); r[1]=(float)((qv.x>>8 ) & 255u); \
  r[2]=(float)((qv.x>>16) & 255u); r[3]=(float)((qv.x>>24)       ); \
  r[4]=(float)( qv.y      & 255u); r[5]=(float)((qv.y>>8 ) & 255u); \
  r[6]=(float)((qv.y>>16) & 255u); r[7]=(float)((qv.y>>24)       );

// ---------------- dec1: block=(b,d); enc u8 in LDS; quad split (8ch/thread) ----------------
// FINAL streamed form (R6/R9/R15-measured, 483 us). Register preload of whh is
// impossible: the allocator pins 1024-thread kernels to 64 VGPR; neither
// __launch_bounds__(,4) (R8) nor amdgpu_waves_per_eu(4,4) (R11) raises it —
// preload arrays spill to scratch (R7: 3.1GB, R11: 1.2GB FETCH). Do not retry.
__global__ __launch_bounds__(1024) void k_dec1g(
    const uint4* __restrict__ encq,        // [B][L3C][2] uint4 (32 x u8)
    const float* __restrict__ encs,        // [B][L3C] rowscale
    const float* __restrict__ attn_w,      // [256][32]
    const uint4* __restrict__ wihT,        // [2][4][1024] f16x8 (K=32)
    const uint4* __restrict__ whhT,        // [2][32][1024] f16x8 (K=256)
    const float* __restrict__ bih, const float* __restrict__ bhh,
    float* __restrict__ d2in)              // [B][60][512]
{
  int b = blockIdx.x, d = blockIdx.y, tid = threadIdx.x;
  int c = tid & 3, rb = tid >> 2;          // quad covers rows rb+256k, k=0..15; lane owns ch c*8..c*8+7

  __shared__ __align__(16) uint2 encQ2[16384];  // 128 KB: row l = 4 uint2 (32 x u8)
  __shared__ float sls[4096];                   // 16 KB rowscales
  __shared__ __align__(16) float hls[256];      // fp32 h (attention matvec input)
  __shared__ __align__(16) unsigned h2pk[128];  // h packed f16x2 (gate dot input)
  __shared__ __align__(16) unsigned ctxh[16];   // ctx packed f16x2
  __shared__ float vl[32];
  __shared__ float maxenc[32];
  __shared__ float Msh;
  __shared__ float red[1024];
  __shared__ float scr[512];                    // [16 waves][32 ch]
  __shared__ float gls[1024];

  { // stage enc slice once (uint4-coalesced)
    const uint4* src = encq + (size_t)b*L3C*2;
    uint4* dst = (uint4*)encQ2;
    for (int i = tid; i < 8192; i += 1024)
      dst[i] = (i < L3C*2) ? src[i] : make_uint4(0,0,0,0);
    const float* ss = encs + (size_t)b*L3C;
    for (int i = tid; i < 4096; i += 1024)
      sls[i] = (i < L3C) ? ss[i] : 0.f;
  }
  if (tid < 256) hls[tid] = 0.f;
  if (tid < 128) h2pk[tid] = 0u;
  float creg = 0.f;
  float bsum = bih[(size_t)d*1024 + tid] + bhh[(size_t)d*1024 + tid];
  const uint4* whp = whhT + (size_t)d*32768;
  __syncthreads();

  { // one-time: per-channel max of real enc (>=0) -> maxenc[32]
    float mc[8];
#pragma unroll
    for (int j=0;j<8;j++) mc[j] = 0.f;
#pragma unroll
    for (int k=0;k<16;k++){
      int l = rb + 256*k;
      uint2 qv = encQ2[l*4 + c];
      float sl = sls[l];
      float r[8]; CVT8(r, qv)
#pragma unroll
      for (int j=0;j<8;j++) mc[j] = fmaxf(mc[j], r[j]*sl);
    }
#pragma unroll
    for (int off=4; off<=32; off<<=1){
#pragma unroll
      for (int j=0;j<8;j++) mc[j] = fmaxf(mc[j], __shfl_xor(mc[j], off));
    }
    int wid = tid >> 6;
    if ((tid&63) < 4){
#pragma unroll
      for (int j=0;j<8;j++) scr[wid*32 + c*8 + j] = mc[j];
    }
    __syncthreads();
    if (tid < 32){
      float mm = 0.f;
#pragma unroll
      for (int w=0;w<16;w++) mm = fmaxf(mm, scr[w*32 + tid]);
      maxenc[tid] = mm;
    }
    __syncthreads();
  }

  for (int t=0; t<TDEC; t++){
    // -- phase 1: v[c] = sum_u h[u]*attn_w[u][c]; M = sum_c maxenc[c]*max(v,0) --
    {
      int cc = tid & 31, part = tid >> 5;
      const float* wp = attn_w + (size_t)(part*8)*32 + cc;
      float s = 0.f;
#pragma unroll
      for (int k=0;k<8;k++) s = fmaf(hls[part*8+k], wp[k*32], s);
      red[tid] = s;
    }
    __syncthreads();
    if (tid < 32){
      float v = 0.f;
#pragma unroll
      for (int q=0;q<32;q++) v += red[q*32 + tid];
      vl[tid] = v;
      float mt = maxenc[tid] * fmaxf(v, 0.f);
#pragma unroll
      for (int off=1; off<32; off<<=1) mt += __shfl_xor(mt, off);
      if (tid==0) Msh = mt;
    }
    __syncthreads();

    // -- fused phase 2 (enc scoring, static-bound softmax) + whh·h gate stream --
    float vreg[8];
#pragma unroll
    for (int j=0;j<8;j++) vreg[j] = vl[c*8 + j];
    float M = Msh;
    float ssum = 0.f;
    float acc[8];
#pragma unroll
    for (int j=0;j<8;j++) acc[j] = 0.f;
    float g = bsum;                          // whh dots accumulate here (h stable this step)
#pragma unroll 4
    for (int k=0;k<16;k++){
      uint4 wv0 = whp[(2*k  )*1024 + tid];   // whh stream overlapped with scoring
      uint4 wv1 = whp[(2*k+1)*1024 + tid];
      int l = rb + 256*k;
      uint2 qv = encQ2[l*4 + c];
      float sl = sls[l];
      float r[8]; CVT8(r, qv)
      float s = 0.f;
#pragma unroll
      for (int j=0;j<8;j++) s = fmaf(r[j], vreg[j], s);
      s = dppadd<0xB1>(s);                   // quad xor1 (VALU)
      s = dppadd<0x4E>(s);                   // quad xor2 (VALU)
      s *= sl;
      if (l >= L3C) s = -3.0e38f;            // pad rows (only k=15 can trigger)
      float e = __expf(s - M);
      ssum += e;
      float em = e * sl;
#pragma unroll
      for (int j=0;j<8;j++) acc[j] = fmaf(em, r[j], acc[j]);
      uint4 hv0 = *(const uint4*)&h2pk[(2*k  )*4];
      uint4 hv1 = *(const uint4*)&h2pk[(2*k+1)*4];
      DOT8(g, wv0, hv0)
      DOT8(g, wv1, hv1)
    }
    // reduce across quads: row_ror4+ror8 (VALU) then xor16/xor32 (cross-row)
    ssum = dppadd<0x124>(ssum); ssum = dppadd<0x128>(ssum);
    ssum += __shfl_xor(ssum, 16); ssum += __shfl_xor(ssum, 32);
#pragma unroll
    for (int j=0;j<8;j++){
      acc[j] = dppadd<0x124>(acc[j]); acc[j] = dppadd<0x128>(acc[j]);
      acc[j] += __shfl_xor(acc[j], 16); acc[j] += __shfl_xor(acc[j], 32);
    }
    int wid = tid >> 6;
    if ((tid&63) < 4){
#pragma unroll
      for (int j=0;j<8;j++) scr[wid*32 + c*8 + j] = acc[j];
    }
    if ((tid&63)==0) red[wid] = ssum;
    __syncthreads();
    if (tid < 32){
      float S = 0.f, s2 = 0.f;
#pragma unroll
      for (int w=0;w<16;w++){ S += red[w]; s2 += scr[w*32 + tid]; }
      float cv = s2 / S;
      float co = __shfl_xor(cv, 1);
      if (!(tid&1)) ctxh[tid>>1] = pkh2(cv, co);
    }
    __syncthreads();

    // -- wih·ctx (K=32, streamed — cheap) + nonlinearity --
#pragma unroll
    for (int c8=0;c8<4;c8++){
      uint4 wv = wihT[(size_t)d*4096 + c8*1024 + tid];
      uint4 hv = *(const uint4*)&ctxh[c8*4];
      DOT8(g, wv, hv)
    }
    gls[tid] = g;
    __syncthreads();
    if (tid < 256){
      float ii = sigf(gls[tid]);
      float ff = sigf(gls[256+tid]);
      float gg = tanhf(gls[512+tid]);
      float oo = sigf(gls[768+tid]);
      creg = fmaf(ff, creg, ii*gg);
      float hn = oo * tanhf(creg);
      hls[tid] = hn;
      float ho = __shfl_xor(hn, 1);
      if (!(tid&1)) h2pk[tid>>1] = pkh2(hn, ho);
      int tout = d ? (59 - t) : t;
      d2in[((size_t)b*60 + tout)*512 + d*256 + tid] = hn;
    }
    __syncthreads();
  }
}

// ---------------- fp32 GEMM (out-projection only — keeps final output precision) ----------------
__global__ __launch_bounds__(256) void k_gemm(
    const float* __restrict__ A, const float* __restrict__ W,
    float* __restrict__ C, const float* __restrict__ b1, const float* __restrict__ b2,
    int K, int ldc, size_t sW, size_t sC, int sB)
{
  int m0 = blockIdx.x * 128, n0 = blockIdx.y * 128, z = blockIdx.z;
  const float* Wz = W + (size_t)z*sW;
  float* Cz = C + (size_t)z*sC;
  const float* b1z = b1 + (size_t)z*sB;
  const float* b2z = b2 ? (b2 + (size_t)z*sB) : nullptr;
  __shared__ __align__(16) float As[16][132];
  __shared__ __align__(16) float Bs[16][132];
  int tid = threadIdx.x;
  int tx = tid & 15, ty = tid >> 4;
  int r = tid >> 2, c4 = tid & 3;
  float acc[8][8] = {};
  for (int k0=0; k0<K; k0+=16){
#pragma unroll
    for (int h=0; h<2; h++){
      int rr = r + h*64;
      float4 av = *(const float4*)(A  + (size_t)(m0+rr)*K + k0 + c4*4);
      float4 bv = *(const float4*)(Wz + (size_t)(n0+rr)*K + k0 + c4*4);
      As[c4*4+0][rr]=av.x; As[c4*4+1][rr]=av.y; As[c4*4+2][rr]=av.z; As[c4*4+3][rr]=av.w;
      Bs[c4*4+0][rr]=bv.x; Bs[c4*4+1][rr]=bv.y; Bs[c4*4+2][rr]=bv.z; Bs[c4*4+3][rr]=bv.w;
    }
    __syncthreads();
#pragma unroll
    for (int kk=0; kk<16; kk++){
      float a[8], bb[8];
      *(float4*)&a[0]  = *(const float4*)&As[kk][ty*8];
      *(float4*)&a[4]  = *(const float4*)&As[kk][ty*8+4];
      *(float4*)&bb[0] = *(const float4*)&Bs[kk][tx*8];
      *(float4*)&bb[4] = *(const float4*)&Bs[kk][tx*8+4];
#pragma unroll
      for (int i=0;i<8;i++)
#pragma unroll
        for (int j=0;j<8;j++)
          acc[i][j] = fmaf(a[i], bb[j], acc[i][j]);
    }
    __syncthreads();
  }
  float bb1[8];
#pragma unroll
  for (int j=0;j<8;j++){
    int n = n0 + tx*8 + j;
    bb1[j] = b1z[n] + (b2z ? b2z[n] : 0.f);
  }
#pragma unroll
  for (int i=0;i<8;i++){
    int m = m0 + ty*8 + i;
    float o[8];
#pragma unroll
    for (int j=0;j<8;j++) o[j] = acc[i][j] + bb1[j];
    *(float4*)(Cz + (size_t)m*ldc + n0 + tx*8)     = *(const float4*)&o[0];
    *(float4*)(Cz + (size_t)m*ldc + n0 + tx*8 + 4) = *(const float4*)&o[4];
  }
}

// ---------------- f16-dot2 GEMM for the xg projections ----------------
__global__ __launch_bounds__(256) void k_gemmh(
    const float* __restrict__ A, const uint4* __restrict__ WhT,
    float* __restrict__ C, const float* __restrict__ b1, const float* __restrict__ b2,
    int K, int ldc, size_t sW, size_t sC, int sB)
{
  int m0 = blockIdx.x * 128, n0 = blockIdx.y * 128, z = blockIdx.z;
  const uint4* Wz = WhT + (size_t)z*sW;        // sW in uint4 units = (K/8)*1024
  float* Cz = C + (size_t)z*sC;
  const float* b1z = b1 + (size_t)z*sB;
  const float* b2z = b2 ? (b2 + (size_t)z*sB) : nullptr;
  __shared__ __align__(16) unsigned Ash[8][132];   // [kpair][m]
  __shared__ __align__(16) unsigned Bsh[8][132];   // [kpair][n]
  int tid = threadIdx.x;
  int tx = tid & 15, ty = tid >> 4;
  int r = tid >> 2, c4 = tid & 3;
  int nB = tid >> 1, hhB = tid & 1;                // B stage: 128 rows x 2 j8-groups
  float acc[8][8] = {};
  for (int k0=0; k0<K; k0+=16){
#pragma unroll
    for (int h=0; h<2; h++){
      int rr = r + h*64;
      float4 av = *(const float4*)(A + (size_t)(m0+rr)*K + k0 + c4*4);
      Ash[c4*2  ][rr] = pkh2(av.x, av.y);
      Ash[c4*2+1][rr] = pkh2(av.z, av.w);
    }
    {
      uint4 wv = Wz[(size_t)(k0/8 + hhB)*1024 + n0 + nB];
      Bsh[hhB*4+0][nB] = wv.x; Bsh[hhB*4+1][nB] = wv.y;
      Bsh[hhB*4+2][nB] = wv.z; Bsh[hhB*4+3][nB] = wv.w;
    }
    __syncthreads();
#pragma unroll
    for (int kk2=0; kk2<8; kk2++){
      uint4 au0 = *(const uint4*)&Ash[kk2][ty*8];
      uint4 au1 = *(const uint4*)&Ash[kk2][ty*8+4];
      uint4 bu0 = *(const uint4*)&Bsh[kk2][tx*8];
      uint4 bu1 = *(const uint4*)&Bsh[kk2][tx*8+4];
      unsigned au[8] = {au0.x,au0.y,au0.z,au0.w,au1.x,au1.y,au1.z,au1.w};
      unsigned bu[8] = {bu0.x,bu0.y,bu0.z,bu0.w,bu1.x,bu1.y,bu1.z,bu1.w};
#pragma unroll
      for (int i=0;i<8;i++)
#pragma unroll
        for (int j=0;j<8;j++)
          acc[i][j] = dot2f(au[i], bu[j], acc[i][j]);
    }
    __syncthreads();
  }
  float bb1[8];
#pragma unroll
  for (int j=0;j<8;j++){
    int n = n0 + tx*8 + j;
    bb1[j] = b1z[n] + (b2z ? b2z[n] : 0.f);
  }
#pragma unroll
  for (int i=0;i<8;i++){
    int m = m0 + ty*8 + i;
    float o[8];
#pragma unroll
    for (int j=0;j<8;j++) o[j] = acc[i][j] + bb1[j];
    *(float4*)(Cz + (size_t)m*ldc + n0 + tx*8)     = *(const float4*)&o[0];
    *(float4*)(Cz + (size_t)m*ldc + n0 + tx*8 + 4) = *(const float4*)&o[4];
  }
}

// ---------------- dec2: recurrent, block = (dir, batch), 16 waves ----------------
// R9-MEASURED FORM (restored): wpre[20] + amdgpu_waves_per_eu(4,4).
// R15 A/B: removing these cost +147us on non-dec1g (1131 -> 1278). The
// mechanism is uncertain (attribute changes scheduling even at fixed VGPR
// count; loop-invariant preload addresses batch better), but the measurement
// is decisive. Keep exactly this form.
__global__ __launch_bounds__(1024) __attribute__((amdgpu_waves_per_eu(4,4)))
void k_rec2(
    const float* __restrict__ xg,   // [2][64][60][1024]
    const uint4* __restrict__ wT,   // [2][32][1024] f16x8
    float* __restrict__ out)        // [64][60][512]
{
  int b = blockIdx.x, d = blockIdx.y, tid = threadIdx.x;
  __shared__ __align__(16) unsigned h2pk[128];  // h packed f16x2
  __shared__ float gls[1024];
  float c = 0.f;
  if (tid < 128) h2pk[tid] = 0u;
  const uint4* wp = wT + (size_t)d*32*1024;
  uint4 wpre[20];
#pragma unroll
  for (int j=0;j<20;j++) wpre[j] = wp[j*1024 + tid];   // once, not per step
  const float* xp = xg + (((size_t)d*64 + b)*60)*1024;
  __syncthreads();
  for (int step=0; step<TDEC; step++){
    int t = d ? (TDEC-1-step) : step;
    float g = xp[(size_t)t*1024 + tid];
#pragma unroll
    for (int j8=0;j8<20;j8++){                          // preloaded part
      uint4 hv = *(const uint4*)&h2pk[j8*4];
      DOT8(g, wpre[j8], hv)
    }
#pragma unroll 4
    for (int j8=20;j8<32;j8++){                         // streamed part
      uint4 wv = wp[j8*1024 + tid];
      uint4 hv = *(const uint4*)&h2pk[j8*4];
      DOT8(g, wv, hv)
    }
    gls[tid] = g;
    __syncthreads();
    if (tid < 256){
      float ii = sigf(gls[tid]);
      float ff = sigf(gls[256+tid]);
      float gg = tanhf(gls[512+tid]);
      float oo = sigf(gls[768+tid]);
      c = fmaf(ff, c, ii*gg);
      float hn = oo * tanhf(c);
      float ho = __shfl_xor(hn, 1);
      if (!(tid&1)) h2pk[tid>>1] = pkh2(hn, ho);
      out[((size_t)b*60 + t)*512 + d*256 + tid] = hn;
    }
    __syncthreads();
  }
}

extern "C" void kernel_launch(void* const* d_in, const int* in_sizes, int n_in,
                              void* d_out, int out_size, void* d_ws, size_t ws_size,
                              hipStream_t stream) {
  const float* x      = (const float*)d_in[0];
  const float* cw1    = (const float*)d_in[1];
  const float* cb1    = (const float*)d_in[2];
  const float* cw2    = (const float*)d_in[3];
  const float* cb2    = (const float*)d_in[4];
  const float* cw3    = (const float*)d_in[5];
  const float* cb3    = (const float*)d_in[6];
  const float* attn_w = (const float*)d_in[7];
  // d_in[8] attn_b: constant over softmax axis -> drops out analytically
  const float* d1_wih = (const float*)d_in[9];
  const float* d1_whh = (const float*)d_in[10];
  const float* d1_bih = (const float*)d_in[11];
  const float* d1_bhh = (const float*)d_in[12];
  const float* w2_ih0 = (const float*)d_in[13];
  const float* w2_hh0 = (const float*)d_in[14];
  const float* b2_ih0 = (const float*)d_in[15];
  const float* b2_hh0 = (const float*)d_in[16];
  const float* w2_ih1 = (const float*)d_in[17];
  const float* w2_hh1 = (const float*)d_in[18];
  const float* b2_ih1 = (const float*)d_in[19];
  const float* b2_hh1 = (const float*)d_in[20];
  const float* out_w  = (const float*)d_in[21];
  const float* out_b  = (const float*)d_in[22];

  char* ws = (char*)d_ws;
  size_t off = 0;
  // enc region: u8 enc (8.34 MB) + rowscales (1.04 MB). Dead after dec1g —
  // reused for the dec2 weight packs (6.3 MB), packed AFTER dec1g completes.
  uint4* encq = (uint4*)(ws + off);                                // [B][L3C][2] uint4
  float* encs = (float*)(ws + off + 8338432);                      // [B][L3C]
  uint4* wih0T = (uint4*)(ws + 0);                                 // 2 MB
  uint4* wih1T = (uint4*)(ws + 2097152);                           // 2 MB
  uint4* whh0T = (uint4*)(ws + 4194304);                           // 1 MB
  uint4* whh1T = (uint4*)(ws + 5242880);                           // 1 MB
  off += 16675840;
  size_t off_h1 = off;
  float* h1buf = (float*)(ws + off); off += 8382464;               // (B,4093,8)
  float* h2buf = (float*)(ws + off); off += 16736256;              // (B,4086,16)
  float* d2in  = (float*)(ws + off_h1);                            // reuse: (B,60,512)
  float* l0    = (float*)(ws + off_h1 + 7864320);
  float* l1    = (float*)(ws + off_h1 + 15728640);
  float* xg    = (float*)(ws + off); off += 31457280;              // [2][B][60][1024]
  // dec1 packs live INSIDE the xg region (xg written only after dec1 completes)
  uint4* d1whhT = (uint4*)xg;                                      // 1 MB
  uint4* d1wihT = (uint4*)((char*)xg + 1048576);                   // +128 KB
  (void)ws_size; (void)in_sizes; (void)n_in; (void)out_size;

  // dec1 weight packs (before dec1; clobbered later by xg — fine)
  k_packwh<<<256,256,0,stream>>>(d1_whh, d1whhT, 256);
  k_packwh<<<32, 256,0,stream>>>(d1_wih, d1wihT, 32);

  k_convL<64,8,4,65><<<dim3(16,B_),256,0,stream>>>(x, cw1, cb1, h1buf, 4096, L1C);
  k_convL<8,16,8,9><<<dim3(16,B_),256,0,stream>>>(h1buf, cw2, cb2, h2buf, L1C, L2C);
  k_conv3qL<<<dim3(16,B_),256,0,stream>>>(h2buf, cw3, cb3, encq, encs, L2C, L3C);

  // dec1: 128 independent blocks (b,d); enc u8 in LDS; fused score+gate stream
  k_dec1g<<<dim3(64,2),1024,0,stream>>>(encq, encs, attn_w, d1wihT, d1whhT,
                                        d1_bih, d1_bhh, d2in);

  // dec2 weight packs into the (now dead) enc region
  k_packwh<<<512,256,0,stream>>>(w2_ih0, wih0T, 512);
  k_packwh<<<512,256,0,stream>>>(w2_ih1, wih1T, 512);
  k_packwh<<<256,256,0,stream>>>(w2_hh0, whh0T, 256);
  k_packwh<<<256,256,0,stream>>>(w2_hh1, whh1T, 256);

  // dec2 layer 0 (f16-dot2 xg GEMM)
  k_gemmh<<<dim3(30,8,2),256,0,stream>>>(d2in, wih0T, xg, b2_ih0, b2_hh0,
                                         512, 1024, (size_t)64*1024, (size_t)3840*1024, 1024);
  k_rec2<<<dim3(64,2),1024,0,stream>>>(xg, whh0T, l0);
  // dec2 layer 1
  k_gemmh<<<dim3(30,8,2),256,0,stream>>>(l0, wih1T, xg, b2_ih1, b2_hh1,
                                         512, 1024, (size_t)64*1024, (size_t)3840*1024, 1024);
  k_rec2<<<dim3(64,2),1024,0,stream>>>(xg, whh1T, l1);
  // output projection (fp32 — final output precision)
  k_gemm<<<dim3(30,1,1),256,0,stream>>>(l1, out_w, (float*)d_out, out_b, nullptr,
                                        512, 128, 0, 0, 0);
}